// Round 9
// baseline (150.451 us; speedup 1.0000x reference)
//
#include <hip/hip_runtime.h>
#include <stdint.h>

#define INF    4096
#define OUTF   11008
#define NTOK   256
#define QZ_COLS (OUTF / 8)   // 1376
#define NTILES  (INF / 128)  // 32 K-tiles, one quant group each

#define BM 64
#define BN 64

typedef __attribute__((ext_vector_type(8))) _Float16 f16x8;
typedef __attribute__((ext_vector_type(2))) _Float16 f16x2;
typedef __attribute__((ext_vector_type(4))) float    f32x4;

// Raw barrier: make our ds_writes visible (lgkmcnt(0)) but do NOT drain vmcnt —
// in-flight global prefetches stay in flight across the barrier (T3/T4 mechanism).
#define BAR() do { \
    asm volatile("s_waitcnt lgkmcnt(0)" ::: "memory"); \
    __builtin_amdgcn_s_barrier(); \
} while (0)

#define DECL_SET(S) \
    f32x4 pv0##S[4], pv1##S[4]; uint32_t pw##S[4]; int pzw##S; float psj0##S, psj1##S;

#define ISSUE(S, T) do { \
    const int _t = (T); \
    _Pragma("unroll") for (int r = 0; r < 4; ++r) { \
        const float* _src = x + (size_t)(m0 + a_m + r * 16) * INF + _t * 128 + a_kc * 8; \
        pv0##S[r] = *(const f32x4*)_src; \
        pv1##S[r] = *(const f32x4*)(_src + 4); } \
    _Pragma("unroll") for (int r = 0; r < 4; ++r) \
        pw##S[r] = (uint32_t)qweight[(size_t)(_t * 16 + r * 4 + thi) * OUTF + n0 + oL]; \
    pzw##S  = qzeros[_t * QZ_COLS + zwordIdx]; \
    psj0##S = scales[_t * OUTF + n0 + wn * 32 + l15]; \
    psj1##S = scales[_t * OUTF + n0 + wn * 32 + 16 + l15]; \
} while (0)

// Dequant reg-set S into LDS buffer BUF (compile-time 0/1); records its scales as "next".
#define DEQUANT(S, BUF) do { \
    const int _z = ((pzw##S >> zsh) & 15) + 1; \
    const _Float16 _hz = (_Float16)(float)(1024 + _z); \
    const f16x2 _z2 = {_hz, _hz}; \
    _Pragma("unroll") for (int r = 0; r < 4; ++r) { \
        uint32_t d[4]; \
        _Pragma("unroll") for (int p = 0; p < 4; ++p) \
            d[p] = __builtin_bit_cast(uint32_t, \
                      __builtin_amdgcn_cvt_pkrtz(pv0##S[r][p], pv1##S[r][p])); \
        *(uint4*)&A_sh[BUF][a_kc][(a_m + r * 16) ^ (a_kc & 7)][0] = \
            make_uint4(d[0], d[1], d[2], d[3]); } \
    _Pragma("unroll") for (int r = 0; r < 4; ++r) { \
        uint32_t d[4]; \
        _Pragma("unroll") for (int p = 0; p < 4; ++p) { \
            const uint32_t bv = ((pw##S[r] >> (4 * p)) & 0x000F000Fu) | 0x64006400u; \
            d[p] = __builtin_bit_cast(uint32_t, __builtin_bit_cast(f16x2, bv) - _z2); } \
        *(uint4*)&B_sh[BUF][r * 4 + thi][oL][0] = make_uint4(d[0], d[1], d[2], d[3]); } \
    cs0_nxt = psj0##S; cs1_nxt = psj1##S; \
} while (0)

#define COMPUTE(BUF) do { \
    _Pragma("unroll") for (int kk = 0; kk < 4; ++kk) { \
        const int k8 = kk * 4 + l4; \
        f16x8 a[2], b[2]; \
        _Pragma("unroll") for (int i = 0; i < 2; ++i) \
            a[i] = *(const f16x8*)&A_sh[BUF][k8][(wm * 32 + i * 16 + l15) ^ (k8 & 7)][0]; \
        _Pragma("unroll") for (int j = 0; j < 2; ++j) \
            b[j] = *(const f16x8*)&B_sh[BUF][k8][wn * 32 + j * 16 + l15][0]; \
        _Pragma("unroll") for (int i = 0; i < 2; ++i) \
            _Pragma("unroll") for (int j = 0; j < 2; ++j) \
                accg[i][j] = __builtin_amdgcn_mfma_f32_16x16x32_f16( \
                                 a[i], b[j], accg[i][j], 0, 0, 0); \
    } \
    _Pragma("unroll") for (int i = 0; i < 2; ++i) { \
        _Pragma("unroll") for (int r = 0; r < 4; ++r) { \
            acc[i][0][r] += cs0_cur * accg[i][0][r]; \
            acc[i][1][r] += cs1_cur * accg[i][1][r]; } \
        accg[i][0] = f32x4{0.f, 0.f, 0.f, 0.f}; \
        accg[i][1] = f32x4{0.f, 0.f, 0.f, 0.f}; } \
} while (0)

__global__ __launch_bounds__(256, 2)
void qlin_mfma(const float* __restrict__ x,
               const float* __restrict__ scales,
               const float* __restrict__ bias,
               const int*   __restrict__ qweight,
               const int*   __restrict__ qzeros,
               float*       __restrict__ out)
{
    // double-buffered: [buf][k8][row][4 dwords = 8 f16]
    __shared__ uint32_t A_sh[2][16][BM][4];   // 32 KiB
    __shared__ uint32_t B_sh[2][16][BN][4];   // 32 KiB

    const int tid = threadIdx.x;
    const int n0  = blockIdx.x * BN;
    const int m0  = blockIdx.y * BM;

    const int lane = tid & 63;
    const int wid  = tid >> 6;
    const int wm   = wid >> 1;   // 0..1 : 32-row slab
    const int wn   = wid & 1;    // 0..1 : 32-col slab
    const int l15  = lane & 15;
    const int l4   = lane >> 4;  // 0..3

    float acc[2][2][4];
    f32x4 accg[2][2];
    #pragma unroll
    for (int i = 0; i < 2; ++i)
        #pragma unroll
        for (int j = 0; j < 2; ++j) {
            accg[i][j] = f32x4{0.f, 0.f, 0.f, 0.f};
            #pragma unroll
            for (int r = 0; r < 4; ++r) acc[i][j][r] = 0.f;
        }

    const int oL  = tid & 63;
    const int thi = tid >> 6;   // 0..3
    const int zsh = (oL & 7) * 4;
    const int zwordIdx = (n0 + oL) >> 3;
    const int a_kc = tid & 15;
    const int a_m  = tid >> 4;

    DECL_SET(A)
    DECL_SET(B)
    float cs0_cur, cs1_cur, cs0_nxt, cs1_nxt;

    // ---- prologue: stage tile 0 into buf0; tile 1 loads in flight ----
    ISSUE(A, 0);
    DEQUANT(A, 0);          // sets nxt = scales(0)
    ISSUE(B, 1);
    BAR();

    // ---- main loop: 2 tiles per iteration, one barrier per tile ----
    for (int t = 0; t < NTILES; t += 2) {
        // even tile t: compute buf0, stage tile t+1 (set B) into buf1
        cs0_cur = cs0_nxt; cs1_cur = cs1_nxt;       // scales(t)
        if (t + 2 < NTILES) ISSUE(A, t + 2);
        COMPUTE(0);
        DEQUANT(B, 1);                              // tile t+1 -> buf1, nxt = scales(t+1)
        BAR();

        // odd tile t+1: compute buf1, stage tile t+2 (set A) into buf0
        cs0_cur = cs0_nxt; cs1_cur = cs1_nxt;       // scales(t+1)
        if (t + 3 < NTILES) ISSUE(B, t + 3);
        COMPUTE(1);
        if (t + 2 < NTILES) {
            DEQUANT(A, 0);                          // tile t+2 -> buf0
            BAR();
        }
    }

    // ---- epilogue: C[row][col] = acc + bias, row=(lane>>4)*4+reg, col=lane&15 ----
    #pragma unroll
    for (int j = 0; j < 2; ++j) {
        const int col = n0 + wn * 32 + j * 16 + l15;
        const float bv = bias[col];
        #pragma unroll
        for (int i = 0; i < 2; ++i) {
            const int row0 = m0 + wm * 32 + i * 16 + l4 * 4;
            #pragma unroll
            for (int r = 0; r < 4; ++r)
                out[(size_t)(row0 + r) * OUTF + col] = acc[i][j][r] + bv;
        }
    }
}

extern "C" void kernel_launch(void* const* d_in, const int* in_sizes, int n_in,
                              void* d_out, int out_size, void* d_ws, size_t ws_size,
                              hipStream_t stream)
{
    const float* x       = (const float*)d_in[0];
    const float* scales  = (const float*)d_in[1];
    const float* bias    = (const float*)d_in[2];
    const int*   qweight = (const int*)d_in[3];
    const int*   qzeros  = (const int*)d_in[4];
    // d_in[5] = g_idx : deterministic (i // 128), not needed on device
    float* out = (float*)d_out;

    dim3 grid(OUTF / BN, NTOK / BM);  // (172, 4) = 688 blocks, ~2.7/CU
    qlin_mfma<<<grid, dim3(256), 0, stream>>>(x, scales, bias, qweight, qzeros, out);
}

// Round 12
// 131.780 us; speedup vs baseline: 1.1417x; 1.1417x over previous
//
#include <hip/hip_runtime.h>
#include <stdint.h>

#define INF    4096
#define OUTF   11008
#define NTOK   256
#define QZ_COLS (OUTF / 8)   // 1376
#define NTILES  (INF / 128)  // 32 K-tiles, one quant group each

#define BM 64
#define BN 32

typedef __attribute__((ext_vector_type(8))) _Float16 f16x8;
typedef __attribute__((ext_vector_type(2))) _Float16 f16x2;
typedef __attribute__((ext_vector_type(4))) float    f32x4;

typedef const __attribute__((address_space(1))) uint4 gl_uint4;
typedef __attribute__((address_space(3)))       uint4 sh_uint4;

// ---------------------------------------------------------------------------
// Pre-pass: x [256][4096] f32  ->  xw f16 in GEMM-staged layout (d_ws, 2 MB):
//   xw[m_blk(4)][t(32)][k8(16)][mslot(64)] : 16B unit = 8 f16,
//   word p = (col k8*8+p, col k8*8+p+4) pair  (cvt_pkrtz lo/hi),
//   mslot holds row  m0 + (mslot ^ (k8&7))    (XOR-perm baked in).
// Coalesced reads (32B/lane along a row), scattered 16B writes.
// ---------------------------------------------------------------------------
__global__ __launch_bounds__(256, 2)
void xpack(const float* __restrict__ x, uint4* __restrict__ xw)
{
    const int g  = blockIdx.x * 256 + threadIdx.x;   // 131072 threads
    const int m  = g >> 9;          // row 0..255
    const int c8 = g & 511;         // col-octet
    const int t  = c8 >> 4;
    const int k8 = c8 & 15;

    const float* src = x + (size_t)m * INF + c8 * 8;
    const f32x4 v0 = *(const f32x4*)src;
    const f32x4 v1 = *(const f32x4*)(src + 4);
    uint32_t d[4];
    #pragma unroll
    for (int p = 0; p < 4; ++p)
        d[p] = __builtin_bit_cast(uint32_t, __builtin_amdgcn_cvt_pkrtz(v0[p], v1[p]));

    const int mslot = (m & 63) ^ (k8 & 7);
    const size_t oi = ((size_t)(m >> 6) * 32 + t) * 1024 + k8 * 64 + mslot;
    xw[oi] = make_uint4(d[0], d[1], d[2], d[3]);
}

// ---------------------------------------------------------------------------
// GEMM: A staged via global_load_lds (linear LDS dest, layout pre-baked);
// B dequant with zero AND scale folded in (f16 pk ops); MFMA into acc direct.
// ---------------------------------------------------------------------------
__global__ __launch_bounds__(256, 6)
void qlin_mfma(const uint4* __restrict__ xw,
               const float* __restrict__ scales,
               const float* __restrict__ bias,
               const int*   __restrict__ qweight,
               const int*   __restrict__ qzeros,
               float*       __restrict__ out)
{
    __shared__ uint4 A_sh[16][64];   // 16 KiB : [k8][mslot]
    __shared__ uint4 B_sh[16][32];   //  8 KiB : [k8][col]

    const int tid   = threadIdx.x;
    const int n0    = blockIdx.x * BN;
    const int m_blk = blockIdx.y;
    const int m0    = m_blk * BM;

    const int lane = tid & 63;
    const int wid  = tid >> 6;
    const int wm   = wid >> 1;   // 0..1 : 32-row slab
    const int wn   = wid & 1;    // 0..1 : 16-col slab
    const int l15  = lane & 15;
    const int l4   = lane >> 4;  // 0..3

    f32x4 acc[2] = { f32x4{0.f,0.f,0.f,0.f}, f32x4{0.f,0.f,0.f,0.f} };

    // B staging map: col oL, k8 = bk8 and bk8+8
    const int oL  = tid & 31;
    const int bk8 = tid >> 5;            // 0..7
    const int zsh = (oL & 7) * 4;
    const int zcol = (n0 + oL) >> 3;

    const uint4* abase = xw + (size_t)m_blk * 32 * 1024;

    for (int t = 0; t < NTILES; ++t) {
        // ---- B raw loads (longest dep chain first) ----
        const uint32_t w0 = (uint32_t)qweight[(size_t)(t * 16 + bk8)     * OUTF + n0 + oL];
        const uint32_t w1 = (uint32_t)qweight[(size_t)(t * 16 + bk8 + 8) * OUTF + n0 + oL];
        const int   zw = qzeros[t * QZ_COLS + zcol];
        const float sf = scales[t * OUTF + n0 + oL];

        // ---- A stage: 4 x global_load_lds (wave wid covers k8 = wid*4+r) ----
        #pragma unroll
        for (int r = 0; r < 4; ++r) {
            const int k8 = wid * 4 + r;
            const uint4* gp = abase + (size_t)t * 1024 + k8 * 64 + lane;
            __builtin_amdgcn_global_load_lds((gl_uint4*)gp, (sh_uint4*)&A_sh[k8][0],
                                             16, 0, 0);
        }

        // ---- B dequant: ((q+1024) - (z+1024)) * s, all f16 packed ----
        const int z = ((zw >> zsh) & 15) + 1;
        const _Float16 hz = (_Float16)(float)(1024 + z);
        const f16x2 z2 = {hz, hz};
        const _Float16 hs = (_Float16)sf;
        const f16x2 s2 = {hs, hs};
        uint32_t d0[4], d1[4];
        #pragma unroll
        for (int p = 0; p < 4; ++p) {
            const uint32_t b0 = ((w0 >> (4 * p)) & 0x000F000Fu) | 0x64006400u;
            const uint32_t b1 = ((w1 >> (4 * p)) & 0x000F000Fu) | 0x64006400u;
            d0[p] = __builtin_bit_cast(uint32_t,
                        (__builtin_bit_cast(f16x2, b0) - z2) * s2);
            d1[p] = __builtin_bit_cast(uint32_t,
                        (__builtin_bit_cast(f16x2, b1) - z2) * s2);
        }
        *(uint4*)&B_sh[bk8][oL]     = make_uint4(d0[0], d0[1], d0[2], d0[3]);
        *(uint4*)&B_sh[bk8 + 8][oL] = make_uint4(d1[0], d1[1], d1[2], d1[3]);

        __syncthreads();   // drains vmcnt (gll) + lgkmcnt (ds_write)

        // ---- compute: 4 k-steps, 2 MFMA each ----
        #pragma unroll
        for (int kk = 0; kk < 4; ++kk) {
            const int k8 = kk * 4 + l4;
            const f16x8 a0 = __builtin_bit_cast(f16x8, A_sh[k8][(wm * 32      + l15) ^ (k8 & 7)]);
            const f16x8 a1 = __builtin_bit_cast(f16x8, A_sh[k8][(wm * 32 + 16 + l15) ^ (k8 & 7)]);
            const f16x8 b  = __builtin_bit_cast(f16x8, B_sh[k8][wn * 16 + l15]);
            acc[0] = __builtin_amdgcn_mfma_f32_16x16x32_f16(a0, b, acc[0], 0, 0, 0);
            acc[1] = __builtin_amdgcn_mfma_f32_16x16x32_f16(a1, b, acc[1], 0, 0, 0);
        }

        __syncthreads();
    }

    // ---- epilogue: row=(lane>>4)*4+reg, col=lane&15 ----
    const int col = n0 + wn * 16 + l15;
    const float bv = bias[col];
    #pragma unroll
    for (int i = 0; i < 2; ++i) {
        const int row0 = m0 + wm * 32 + i * 16 + l4 * 4;
        #pragma unroll
        for (int r = 0; r < 4; ++r)
            out[(size_t)(row0 + r) * OUTF + col] = acc[i][r] + bv;
    }
}

extern "C" void kernel_launch(void* const* d_in, const int* in_sizes, int n_in,
                              void* d_out, int out_size, void* d_ws, size_t ws_size,
                              hipStream_t stream)
{
    const float* x       = (const float*)d_in[0];
    const float* scales  = (const float*)d_in[1];
    const float* bias    = (const float*)d_in[2];
    const int*   qweight = (const int*)d_in[3];
    const int*   qzeros  = (const int*)d_in[4];
    // d_in[5] = g_idx : deterministic (i // 128), not needed on device
    float* out = (float*)d_out;
    uint4* xw  = (uint4*)d_ws;   // 2 MiB staged-f16 copy of x

    xpack<<<dim3(512), dim3(256), 0, stream>>>(x, xw);
    dim3 grid(OUTF / BN, NTOK / BM);  // (344, 4) = 1376 blocks, ~5.4/CU
    qlin_mfma<<<grid, dim3(256), 0, stream>>>(xw, scales, bias, qweight, qzeros, out);
}